// Round 4
// baseline (22.542 us; speedup 1.0000x reference)
//
#include <hip/hip_runtime.h>

// Conv2d 3x3 pad1: x(2,64,112,112) f32, w(64,64,3,3) f32, bias(64) f32 -> out(2,64,112,112) f32
// Two kernels:
//   1) prep_all: NCHW->padded-NHWC bf16 x-transform (912 blocks, 8 loads/thread)
//                + [tap][oc][ic] bf16 weight transform (36 blocks)
//   2) conv_lds: implicit GEMM on mfma_f32_32x32x16_bf16 (was 16x16x32 — halves LDS/MFMA
//                issue count), weights in XOR-swizzled LDS, A direct 16B global loads.
//      Block = 64px x 64oc, 4 waves = 2 px-groups x 2 oc-groups of 32px x 32oc.

#define IN_C  64
#define OUT_C 64
#define BN    2
#define HH    112
#define WW    112
#define HP    114
#define WP    114
#define HW    (HH * WW)
#define NXBLK (BN * HP * 4)      // 912: (b, yp, channel-quad)
#define NWBLK 36                 // 36 * 256 * f32x4 = all 36864 floats of w
#define NCONV 392                // 2 * 28 * 7 tiles (4 rows x 16 cols x 64 oc)

typedef __attribute__((ext_vector_type(8)))  short          bf16x8;
typedef __attribute__((ext_vector_type(8)))  unsigned short u16x8;
typedef __attribute__((ext_vector_type(4)))  float          f32x4;
typedef __attribute__((ext_vector_type(16))) float          f32x16;

static __device__ __forceinline__ unsigned short f2bf(float f) {
    unsigned int u = __builtin_bit_cast(unsigned int, f);
    u += 0x7FFFu + ((u >> 16) & 1u);   // round-nearest-even
    return (unsigned short)(u >> 16);
}

// blocks [0, NXBLK): x-transform. block = (b, yp, cq); thread = (xp, 8-channel group).
// blocks [NXBLK, NXBLK+NWBLK): w-transform.
__global__ __launch_bounds__(256) void prep_all(const float* __restrict__ x,
                                                const float* __restrict__ w,
                                                unsigned short* __restrict__ xt,
                                                unsigned short* __restrict__ wt) {
    int blk = blockIdx.x;
    int tid = threadIdx.x;
    if (blk < NXBLK) {
        int cq = blk & 3;
        int r  = blk >> 2;
        int b  = r / HP;
        int yp = r % HP;
        int xp = tid & 127;                    // 0..127, valid < 114
        int ch = cq * 16 + (tid >> 7) * 8;     // 8 channels per thread
        if (xp >= WP) return;
        unsigned short* dst = xt + (((size_t)b * HP + yp) * WP + xp) * IN_C + ch;
        bool border = (yp == 0) | (yp == HP - 1) | (xp == 0) | (xp == WP - 1);
        if (border) {
            u16x8 z = {0, 0, 0, 0, 0, 0, 0, 0};
            *reinterpret_cast<u16x8*>(dst) = z;
        } else {
            const float* src = x + ((size_t)b * IN_C + ch) * HW + (yp - 1) * WW + (xp - 1);
            u16x8 v;
#pragma unroll
            for (int j = 0; j < 8; ++j)
                v[j] = f2bf(src[(size_t)j * HW]);
            *reinterpret_cast<u16x8*>(dst) = v;
        }
    } else {
        int t = (blk - NXBLK) * 256 + tid;     // 0..9215
        f32x4 v = reinterpret_cast<const f32x4*>(w)[t];
#pragma unroll
        for (int j = 0; j < 4; ++j) {
            int e   = 4 * t + j;               // (oc*64+ic)*9 + tap
            int tap = e % 9;
            int p   = e / 9;                   // oc*64+ic
            wt[(size_t)tap * (OUT_C * IN_C) + p] = f2bf(v[j]);
        }
    }
}

// Implicit GEMM, 32x32x16 bf16 MFMA. Wave = 32 px (2 rows x 16 cols) x 32 oc.
// A frag: lane holds xt[b][y + (lo>>4) + r][x0 + (lo&15) + s][ks*16 + hi*8 ..+7] (16B)
// B frag: lane holds wt[tap][ocg*32 + lo][ks*16 + hi*8 ..+7] from swizzled LDS  (16B)
// D (m74/m101): col(oc) = lane&31, row(px) = (reg&3) + 8*(reg>>2) + 4*hi.
__global__ __launch_bounds__(256, 2) void conv_lds(const unsigned short* __restrict__ xt,
                                                   const unsigned short* __restrict__ wt,
                                                   const float* __restrict__ bias,
                                                   float* __restrict__ out) {
    __shared__ unsigned short lw[9 * OUT_C * IN_C];    // 73728 B
    int tid = threadIdx.x;
    int blk = blockIdx.x;

    // stage wt (36864 shorts): 18 u16x8 per thread, XOR-swizzled
#pragma unroll
    for (int i = 0; i < 18; ++i) {
        int V   = tid + i * 256;               // vec8 index, < 4608
        int row = V >> 3;                      // tap*64 + oc
        int c   = (V & 7) << 3;                // short col within row
        u16x8 v = *reinterpret_cast<const u16x8*>(wt + (size_t)V * 8);
        int cs  = c ^ ((row & 7) << 3);
        *reinterpret_cast<u16x8*>(&lw[row * 64 + cs]) = v;
    }
    __syncthreads();

    int l   = tid & 63;
    int wv  = tid >> 6;                 // wave 0..3
    int ocg = wv & 1;                   // oc group: 0 -> oc 0..31, 1 -> oc 32..63
    int pxg = wv >> 1;                  // px group: rows {0,1} or {2,3} of the 4-row tile
    int b   = blk / 196;
    int rm  = blk % 196;
    int ytile = rm / 7, xtile = rm % 7;
    int y0  = ytile * 4 + pxg * 2;      // first of this wave's 2 output rows
    int x0  = xtile * 16;
    int lo  = l & 31;                   // A: px index (row=lo>>4, col=lo&15); B/D: oc index
    int hi  = l >> 5;                   // k-half (8 elements)

    f32x16 acc = {};

    // A base for this lane's pixel (padded coords: +r rows, +s cols shift the window)
    const unsigned short* xb =
        xt + (((size_t)b * HP + y0 + (lo >> 4)) * WP + x0 + (lo & 15)) * IN_C + hi * 8;
    int ocrow = ocg * 32 + lo;          // B-lane's oc
    int swzb  = (ocrow & 7) << 3;

#pragma unroll
    for (int r = 0; r < 3; ++r) {
#pragma unroll
        for (int s = 0; s < 3; ++s) {
            const unsigned short* xp = xb + (r * WP + s) * IN_C;
            int rowbase = ((r * 3 + s) * OUT_C + ocrow) * 64;
#pragma unroll
            for (int ks = 0; ks < 4; ++ks) {   // K=576 in 36 steps of 16
                bf16x8 a  = *reinterpret_cast<const bf16x8*>(xp + ks * 16);
                int   cs  = (ks * 16 + hi * 8) ^ swzb;
                bf16x8 bb = *reinterpret_cast<const bf16x8*>(&lw[rowbase + cs]);
                acc = __builtin_amdgcn_mfma_f32_32x32x16_bf16(a, bb, acc, 0, 0, 0);
            }
        }
    }

    // Epilogue: reg g*4+q holds px = g*8 + 4*hi + q, oc = ocg*32 + lo.
    float bv = bias[ocrow];
#pragma unroll
    for (int g = 0; g < 4; ++g) {
        int yrow = y0 + (g >> 1);                      // (px>>4)
        int xcol = x0 + (g & 1) * 8 + hi * 4;          // (px&15) base
        f32x4 v;
#pragma unroll
        for (int q = 0; q < 4; ++q) v[q] = acc[g * 4 + q] + bv;
        *reinterpret_cast<f32x4*>(out + (((size_t)b * OUT_C + ocrow) * HH + yrow) * WW + xcol) = v;
    }
}

extern "C" void kernel_launch(void* const* d_in, const int* in_sizes, int n_in,
                              void* d_out, int out_size, void* d_ws, size_t ws_size,
                              hipStream_t stream) {
    const float* x    = (const float*)d_in[0];
    const float* w    = (const float*)d_in[1];
    const float* bias = (const float*)d_in[2];
    float* out        = (float*)d_out;

    unsigned short* xt = (unsigned short*)d_ws;                  // 2*114*114*64 bf16 = 3,326,976 B
    unsigned short* wt = xt + (size_t)BN * HP * WP * IN_C;       // 9*64*64 bf16 = 73,728 B

    prep_all<<<dim3(NXBLK + NWBLK), dim3(256), 0, stream>>>(x, w, xt, wt);
    conv_lds<<<dim3(NCONV), dim3(256), 0, stream>>>(xt, wt, bias, out);
}

// Round 5
// 22.263 us; speedup vs baseline: 1.0126x; 1.0126x over previous
//
#include <hip/hip_runtime.h>

// Conv2d 3x3 pad1: x(2,64,112,112) f32, w(64,64,3,3) f32, bias(64) f32 -> out(2,64,112,112) f32
// Two kernels:
//   1) prep_all: NCHW->padded-NHWC bf16 x-transform (912 blocks, 8 loads/thread)
//                + [tap][oc][ic] bf16 weight transform (36 blocks)
//   2) conv_lds: implicit GEMM on mfma_f32_32x32x16_bf16, weights in XOR-swizzled LDS,
//                A direct 16B global loads. FOUR independent accumulators (one per ks
//                K-slice, summed in epilogue) — round 4's single-acc serial MFMA chain
//                stalled the matrix pipe (22.5us vs 18.6us).
//      Block = 64px x 64oc, 4 waves = 2 px-groups x 2 oc-groups of 32px x 32oc.

#define IN_C  64
#define OUT_C 64
#define BN    2
#define HH    112
#define WW    112
#define HP    114
#define WP    114
#define HW    (HH * WW)
#define NXBLK (BN * HP * 4)      // 912: (b, yp, channel-quad)
#define NWBLK 36                 // 36 * 256 * f32x4 = all 36864 floats of w
#define NCONV 392                // 2 * 28 * 7 tiles (4 rows x 16 cols x 64 oc)

typedef __attribute__((ext_vector_type(8)))  short          bf16x8;
typedef __attribute__((ext_vector_type(8)))  unsigned short u16x8;
typedef __attribute__((ext_vector_type(4)))  float          f32x4;
typedef __attribute__((ext_vector_type(16))) float          f32x16;

static __device__ __forceinline__ unsigned short f2bf(float f) {
    unsigned int u = __builtin_bit_cast(unsigned int, f);
    u += 0x7FFFu + ((u >> 16) & 1u);   // round-nearest-even
    return (unsigned short)(u >> 16);
}

// blocks [0, NXBLK): x-transform. block = (b, yp, cq); thread = (xp, 8-channel group).
// blocks [NXBLK, NXBLK+NWBLK): w-transform.
__global__ __launch_bounds__(256) void prep_all(const float* __restrict__ x,
                                                const float* __restrict__ w,
                                                unsigned short* __restrict__ xt,
                                                unsigned short* __restrict__ wt) {
    int blk = blockIdx.x;
    int tid = threadIdx.x;
    if (blk < NXBLK) {
        int cq = blk & 3;
        int r  = blk >> 2;
        int b  = r / HP;
        int yp = r % HP;
        int xp = tid & 127;                    // 0..127, valid < 114
        int ch = cq * 16 + (tid >> 7) * 8;     // 8 channels per thread
        if (xp >= WP) return;
        unsigned short* dst = xt + (((size_t)b * HP + yp) * WP + xp) * IN_C + ch;
        bool border = (yp == 0) | (yp == HP - 1) | (xp == 0) | (xp == WP - 1);
        if (border) {
            u16x8 z = {0, 0, 0, 0, 0, 0, 0, 0};
            *reinterpret_cast<u16x8*>(dst) = z;
        } else {
            const float* src = x + ((size_t)b * IN_C + ch) * HW + (yp - 1) * WW + (xp - 1);
            u16x8 v;
#pragma unroll
            for (int j = 0; j < 8; ++j)
                v[j] = f2bf(src[(size_t)j * HW]);
            *reinterpret_cast<u16x8*>(dst) = v;
        }
    } else {
        int t = (blk - NXBLK) * 256 + tid;     // 0..9215
        f32x4 v = reinterpret_cast<const f32x4*>(w)[t];
#pragma unroll
        for (int j = 0; j < 4; ++j) {
            int e   = 4 * t + j;               // (oc*64+ic)*9 + tap
            int tap = e % 9;
            int p   = e / 9;                   // oc*64+ic
            wt[(size_t)tap * (OUT_C * IN_C) + p] = f2bf(v[j]);
        }
    }
}

// Implicit GEMM, 32x32x16 bf16 MFMA. Wave = 32 px (2 rows x 16 cols) x 32 oc.
// A frag: lane holds xt[b][y + (lo>>4) + r][x0 + (lo&15) + s][ks*16 + hi*8 ..+7] (16B)
// B frag: lane holds wt[tap][ocg*32 + lo][ks*16 + hi*8 ..+7] from swizzled LDS  (16B)
// D (m74/m101): col(oc) = lane&31, row(px) = (reg&3) + 8*(reg>>2) + 4*hi.
// acc[ks] are 4 independent chains (9 deps each); summed before store.
__global__ __launch_bounds__(256, 2) void conv_lds(const unsigned short* __restrict__ xt,
                                                   const unsigned short* __restrict__ wt,
                                                   const float* __restrict__ bias,
                                                   float* __restrict__ out) {
    __shared__ unsigned short lw[9 * OUT_C * IN_C];    // 73728 B
    int tid = threadIdx.x;
    int blk = blockIdx.x;

    // stage wt (36864 shorts): 18 u16x8 per thread, XOR-swizzled
#pragma unroll
    for (int i = 0; i < 18; ++i) {
        int V   = tid + i * 256;               // vec8 index, < 4608
        int row = V >> 3;                      // tap*64 + oc
        int c   = (V & 7) << 3;                // short col within row
        u16x8 v = *reinterpret_cast<const u16x8*>(wt + (size_t)V * 8);
        int cs  = c ^ ((row & 7) << 3);
        *reinterpret_cast<u16x8*>(&lw[row * 64 + cs]) = v;
    }
    __syncthreads();

    int l   = tid & 63;
    int wv  = tid >> 6;                 // wave 0..3
    int ocg = wv & 1;                   // oc group: 0 -> oc 0..31, 1 -> oc 32..63
    int pxg = wv >> 1;                  // px group: rows {0,1} or {2,3} of the 4-row tile
    int b   = blk / 196;
    int rm  = blk % 196;
    int ytile = rm / 7, xtile = rm % 7;
    int y0  = ytile * 4 + pxg * 2;      // first of this wave's 2 output rows
    int x0  = xtile * 16;
    int lo  = l & 31;                   // A: px index (row=lo>>4, col=lo&15); B/D: oc index
    int hi  = l >> 5;                   // k-half (8 elements)

    f32x16 acc0 = {}, acc1 = {}, acc2 = {}, acc3 = {};

    // A base for this lane's pixel (padded coords: +r rows, +s cols shift the window)
    const unsigned short* xb =
        xt + (((size_t)b * HP + y0 + (lo >> 4)) * WP + x0 + (lo & 15)) * IN_C + hi * 8;
    int ocrow = ocg * 32 + lo;          // B-lane's oc
    int swzb  = (ocrow & 7) << 3;
    float bv  = bias[ocrow];

#pragma unroll
    for (int r = 0; r < 3; ++r) {
#pragma unroll
        for (int s = 0; s < 3; ++s) {
            const unsigned short* xp = xb + (r * WP + s) * IN_C;
            int rowbase = ((r * 3 + s) * OUT_C + ocrow) * 64;

            bf16x8 a0 = *reinterpret_cast<const bf16x8*>(xp + 0 * 16);
            bf16x8 a1 = *reinterpret_cast<const bf16x8*>(xp + 1 * 16);
            bf16x8 a2 = *reinterpret_cast<const bf16x8*>(xp + 2 * 16);
            bf16x8 a3 = *reinterpret_cast<const bf16x8*>(xp + 3 * 16);
            bf16x8 w0 = *reinterpret_cast<const bf16x8*>(&lw[rowbase + ((0 * 16 + hi * 8) ^ swzb)]);
            bf16x8 w1 = *reinterpret_cast<const bf16x8*>(&lw[rowbase + ((1 * 16 + hi * 8) ^ swzb)]);
            bf16x8 w2 = *reinterpret_cast<const bf16x8*>(&lw[rowbase + ((2 * 16 + hi * 8) ^ swzb)]);
            bf16x8 w3 = *reinterpret_cast<const bf16x8*>(&lw[rowbase + ((3 * 16 + hi * 8) ^ swzb)]);
            acc0 = __builtin_amdgcn_mfma_f32_32x32x16_bf16(a0, w0, acc0, 0, 0, 0);
            acc1 = __builtin_amdgcn_mfma_f32_32x32x16_bf16(a1, w1, acc1, 0, 0, 0);
            acc2 = __builtin_amdgcn_mfma_f32_32x32x16_bf16(a2, w2, acc2, 0, 0, 0);
            acc3 = __builtin_amdgcn_mfma_f32_32x32x16_bf16(a3, w3, acc3, 0, 0, 0);
        }
    }

    // Epilogue: reg g*4+q holds px = g*8 + 4*hi + q, oc = ocg*32 + lo.
#pragma unroll
    for (int g = 0; g < 4; ++g) {
        int yrow = y0 + (g >> 1);                      // (px>>4)
        int xcol = x0 + (g & 1) * 8 + hi * 4;          // (px&15) base
        f32x4 v;
#pragma unroll
        for (int q = 0; q < 4; ++q)
            v[q] = acc0[g * 4 + q] + acc1[g * 4 + q] + acc2[g * 4 + q] + acc3[g * 4 + q] + bv;
        *reinterpret_cast<f32x4*>(out + (((size_t)b * OUT_C + ocrow) * HH + yrow) * WW + xcol) = v;
    }
}

extern "C" void kernel_launch(void* const* d_in, const int* in_sizes, int n_in,
                              void* d_out, int out_size, void* d_ws, size_t ws_size,
                              hipStream_t stream) {
    const float* x    = (const float*)d_in[0];
    const float* w    = (const float*)d_in[1];
    const float* bias = (const float*)d_in[2];
    float* out        = (float*)d_out;

    unsigned short* xt = (unsigned short*)d_ws;                  // 2*114*114*64 bf16 = 3,326,976 B
    unsigned short* wt = xt + (size_t)BN * HP * WP * IN_C;       // 9*64*64 bf16 = 73,728 B

    prep_all<<<dim3(NXBLK + NWBLK), dim3(256), 0, stream>>>(x, w, xt, wt);
    conv_lds<<<dim3(NCONV), dim3(256), 0, stream>>>(xt, wt, bias, out);
}

// Round 6
// 19.278 us; speedup vs baseline: 1.1694x; 1.1548x over previous
//
#include <hip/hip_runtime.h>

// Conv2d 3x3 pad1: x(2,64,112,112) f32, w(64,64,3,3) f32, bias(64) f32 -> out(2,64,112,112) f32
// Two kernels:
//   1) prep_all: NCHW->padded-NHWC bf16 x-transform + [tap][oc][ic] bf16 weight transform
//   2) conv_lds: implicit GEMM, 16x16x32 bf16 MFMA, balanced 2x2 fragment wave:
//      wave = 32px (2 rows x 16 cols) x 32oc -> per K-step 2 A-loads + 2 B-reads + 4 MFMAs.
//      (r3: 1A+4B per 4 MFMA = LDS-bound 2.75us; r4/5: 1A+1B per MFMA = A-latency-bound.)
//      Block = 2 waves (64px x 32oc), oc-split LDS 36.9KB, 784 blocks (3 blocks/CU),
//      bijective XCD chunk-swizzle for xt L2 locality.

#define IN_C  64
#define OUT_C 64
#define BN    2
#define HH    112
#define WW    112
#define HP    114
#define WP    114
#define HW    (HH * WW)
#define NXBLK (BN * HP * 4)      // 912: (b, yp, channel-quad)
#define NWBLK 36                 // 36 * 256 * f32x4 = all 36864 floats of w
#define NCONV 784                // 392 spatial tiles (4 rows x 16 cols) x 2 oc-halves

typedef __attribute__((ext_vector_type(8))) short          bf16x8;
typedef __attribute__((ext_vector_type(8))) unsigned short u16x8;
typedef __attribute__((ext_vector_type(4))) float          f32x4;

static __device__ __forceinline__ unsigned short f2bf(float f) {
    unsigned int u = __builtin_bit_cast(unsigned int, f);
    u += 0x7FFFu + ((u >> 16) & 1u);   // round-nearest-even
    return (unsigned short)(u >> 16);
}

// blocks [0, NXBLK): x-transform. block = (b, yp, cq); thread = (xp, 8-channel group).
// blocks [NXBLK, NXBLK+NWBLK): w-transform.
__global__ __launch_bounds__(256) void prep_all(const float* __restrict__ x,
                                                const float* __restrict__ w,
                                                unsigned short* __restrict__ xt,
                                                unsigned short* __restrict__ wt) {
    int blk = blockIdx.x;
    int tid = threadIdx.x;
    if (blk < NXBLK) {
        int cq = blk & 3;
        int r  = blk >> 2;
        int b  = r / HP;
        int yp = r % HP;
        int xp = tid & 127;                    // 0..127, valid < 114
        int ch = cq * 16 + (tid >> 7) * 8;     // 8 channels per thread
        if (xp >= WP) return;
        unsigned short* dst = xt + (((size_t)b * HP + yp) * WP + xp) * IN_C + ch;
        bool border = (yp == 0) | (yp == HP - 1) | (xp == 0) | (xp == WP - 1);
        if (border) {
            u16x8 z = {0, 0, 0, 0, 0, 0, 0, 0};
            *reinterpret_cast<u16x8*>(dst) = z;
        } else {
            const float* src = x + ((size_t)b * IN_C + ch) * HW + (yp - 1) * WW + (xp - 1);
            u16x8 v;
#pragma unroll
            for (int j = 0; j < 8; ++j)
                v[j] = f2bf(src[(size_t)j * HW]);
            *reinterpret_cast<u16x8*>(dst) = v;
        }
    } else {
        int t = (blk - NXBLK) * 256 + tid;     // 0..9215
        f32x4 v = reinterpret_cast<const f32x4*>(w)[t];
#pragma unroll
        for (int j = 0; j < 4; ++j) {
            int e   = 4 * t + j;               // (oc*64+ic)*9 + tap
            int tap = e % 9;
            int p   = e / 9;                   // oc*64+ic
            wt[(size_t)tap * (OUT_C * IN_C) + p] = f2bf(v[j]);
        }
    }
}

// conv: block = 2 waves, 64px x 32oc. Wave wv owns rows {ytile*4+wv*2, +1} x 16 cols.
// LDS holds this block's oc-half of weights: [tap][ocl(32)][ic(64)] XOR-swizzled.
// A frag (px-frag p): lane = xt[b][y0+p+r][x0+(l&15)+s][icc*32 + (l>>4)*8 ..+7]  (16B global)
// B frag (oc-frag f): lane = lw row tap*32+f*16+(l&15), shorts (icc*32+(l>>4)*8)^swz (16B LDS)
// D: col(oc)=l&15, row(px)=4*(l>>4)+reg  [m89]
__global__ __launch_bounds__(128) void conv_lds(const unsigned short* __restrict__ xt,
                                                const unsigned short* __restrict__ wt,
                                                const float* __restrict__ bias,
                                                float* __restrict__ out) {
    __shared__ unsigned short lw[9 * 32 * IN_C];       // 36864 B
    int tid = threadIdx.x;

    // bijective XCD chunk-swizzle: 784 = 8 * 98
    int bid  = blockIdx.x;
    int wgid = (bid & 7) * 98 + (bid >> 3);
    int ocg  = wgid & 1;                // oc half
    int sp   = wgid >> 1;               // 0..391 spatial tile
    int b    = sp / 196;
    int t2   = sp % 196;
    int ytile = t2 / 7, xtile = t2 % 7;

    // stage this oc-half's weights: 2304 u16x8 vecs / 128 thr = 18 per thread
#pragma unroll
    for (int i = 0; i < 18; ++i) {
        int V    = tid + i * 128;              // < 2304
        int lrow = V >> 3;                     // tap*32 + ocl
        int c    = (V & 7) << 3;
        int tap  = lrow >> 5;
        int ocl  = lrow & 31;
        u16x8 v  = *reinterpret_cast<const u16x8*>(
                       wt + ((size_t)(tap << 6) + ocg * 32 + ocl) * IN_C + c);
        int cs   = c ^ ((ocl & 7) << 3);
        *reinterpret_cast<u16x8*>(&lw[lrow * IN_C + cs]) = v;
    }
    __syncthreads();

    int l  = tid & 63;
    int wv = tid >> 6;                  // wave 0..1
    int y0 = ytile * 4 + wv * 2;        // first of this wave's 2 rows
    int x0 = xtile * 16;
    int lm = l & 15;
    int lk = l >> 4;
    int swz = (lm & 7) << 3;

    f32x4 acc00 = {}, acc01 = {}, acc10 = {}, acc11 = {};

    const unsigned short* xb0 = xt + (((size_t)b * HP + y0)     * WP + x0 + lm) * IN_C + lk * 8;
    const unsigned short* xb1 = xt + (((size_t)b * HP + y0 + 1) * WP + x0 + lm) * IN_C + lk * 8;
    int oc0 = ocg * 32 + lm;            // f=0 oc for this lane
    float bv0 = bias[oc0];
    float bv1 = bias[oc0 + 16];

#pragma unroll
    for (int r = 0; r < 3; ++r) {
#pragma unroll
        for (int s = 0; s < 3; ++s) {
            const unsigned short* xp0 = xb0 + (r * WP + s) * IN_C;
            const unsigned short* xp1 = xb1 + (r * WP + s) * IN_C;
            int rb0 = ((r * 3 + s) * 32 + lm) * IN_C;        // f=0 LDS row base
#pragma unroll
            for (int icc = 0; icc < 2; ++icc) {
                int cs = (icc * 32 + lk * 8) ^ swz;
                bf16x8 a0 = *reinterpret_cast<const bf16x8*>(xp0 + icc * 32);
                bf16x8 a1 = *reinterpret_cast<const bf16x8*>(xp1 + icc * 32);
                bf16x8 w0 = *reinterpret_cast<const bf16x8*>(&lw[rb0 + cs]);
                bf16x8 w1 = *reinterpret_cast<const bf16x8*>(&lw[rb0 + 16 * IN_C + cs]);
                acc00 = __builtin_amdgcn_mfma_f32_16x16x32_bf16(a0, w0, acc00, 0, 0, 0);
                acc01 = __builtin_amdgcn_mfma_f32_16x16x32_bf16(a0, w1, acc01, 0, 0, 0);
                acc10 = __builtin_amdgcn_mfma_f32_16x16x32_bf16(a1, w0, acc10, 0, 0, 0);
                acc11 = __builtin_amdgcn_mfma_f32_16x16x32_bf16(a1, w1, acc11, 0, 0, 0);
            }
        }
    }

    // Epilogue: lane l holds px x0+4*lk..+3 (row y0+p) for oc = ocg*32 + f*16 + lm.
    int px = x0 + lk * 4;
    {
        f32x4 v;
        float* o00 = out + (((size_t)b * OUT_C + oc0)      * HH + y0) * WW + px;
        float* o01 = out + (((size_t)b * OUT_C + oc0 + 16) * HH + y0) * WW + px;
        float* o10 = o00 + WW;
        float* o11 = o01 + WW;
#pragma unroll
        for (int q = 0; q < 4; ++q) v[q] = acc00[q] + bv0;
        *reinterpret_cast<f32x4*>(o00) = v;
#pragma unroll
        for (int q = 0; q < 4; ++q) v[q] = acc01[q] + bv1;
        *reinterpret_cast<f32x4*>(o01) = v;
#pragma unroll
        for (int q = 0; q < 4; ++q) v[q] = acc10[q] + bv0;
        *reinterpret_cast<f32x4*>(o10) = v;
#pragma unroll
        for (int q = 0; q < 4; ++q) v[q] = acc11[q] + bv1;
        *reinterpret_cast<f32x4*>(o11) = v;
    }
}

extern "C" void kernel_launch(void* const* d_in, const int* in_sizes, int n_in,
                              void* d_out, int out_size, void* d_ws, size_t ws_size,
                              hipStream_t stream) {
    const float* x    = (const float*)d_in[0];
    const float* w    = (const float*)d_in[1];
    const float* bias = (const float*)d_in[2];
    float* out        = (float*)d_out;

    unsigned short* xt = (unsigned short*)d_ws;                  // 2*114*114*64 bf16 = 3,326,976 B
    unsigned short* wt = xt + (size_t)BN * HP * WP * IN_C;       // 9*64*64 bf16 = 73,728 B

    prep_all<<<dim3(NXBLK + NWBLK), dim3(256), 0, stream>>>(x, w, xt, wt);
    conv_lds<<<dim3(NCONV), dim3(128), 0, stream>>>(xt, wt, bias, out);
}

// Round 7
// 18.776 us; speedup vs baseline: 1.2006x; 1.0267x over previous
//
#include <hip/hip_runtime.h>

// Conv2d 3x3 pad1: x(2,64,112,112) f32, w(64,64,3,3) f32, bias(64) f32 -> out(2,64,112,112) f32
// Two kernels (r3 structure — empirical best 18.65us — plus bijective XCD chunk-swizzle):
//   1) prep_all: NCHW->padded-NHWC bf16 x-transform (912 blocks, 8 loads/thread)
//                + [tap][oc][ic] bf16 weight transform (36 blocks)
//   2) conv_lds: implicit GEMM, mfma_f32_16x16x32_bf16, wave = 16px x 64oc,
//                weights in XOR-swizzled LDS, A-fragments direct 16B global loads.
//                392 blocks = 8 XCD chunks x 49 (bijective swizzle for xt L2 locality).

#define IN_C  64
#define OUT_C 64
#define BN    2
#define HH    112
#define WW    112
#define HP    114
#define WP    114
#define HW    (HH * WW)
#define NXBLK (BN * HP * 4)      // 912: (b, yp, channel-quad)
#define NWBLK 36                 // 36 * 256 * f32x4 = all 36864 floats of w
#define NCONV 392                // 2 * 28 * 7 tiles (4 rows x 16 cols, 4 waves)

typedef __attribute__((ext_vector_type(8))) short          bf16x8;
typedef __attribute__((ext_vector_type(8))) unsigned short u16x8;
typedef __attribute__((ext_vector_type(4))) float          f32x4;

static __device__ __forceinline__ unsigned short f2bf(float f) {
    unsigned int u = __builtin_bit_cast(unsigned int, f);
    u += 0x7FFFu + ((u >> 16) & 1u);   // round-nearest-even
    return (unsigned short)(u >> 16);
}

// blocks [0, NXBLK): x-transform. block = (b, yp, cq); thread = (xp, 8-channel group).
// blocks [NXBLK, NXBLK+NWBLK): w-transform.
__global__ __launch_bounds__(256) void prep_all(const float* __restrict__ x,
                                                const float* __restrict__ w,
                                                unsigned short* __restrict__ xt,
                                                unsigned short* __restrict__ wt) {
    int blk = blockIdx.x;
    int tid = threadIdx.x;
    if (blk < NXBLK) {
        int cq = blk & 3;
        int r  = blk >> 2;
        int b  = r / HP;
        int yp = r % HP;
        int xp = tid & 127;                    // 0..127, valid < 114
        int ch = cq * 16 + (tid >> 7) * 8;     // 8 channels per thread
        if (xp >= WP) return;
        unsigned short* dst = xt + (((size_t)b * HP + yp) * WP + xp) * IN_C + ch;
        bool border = (yp == 0) | (yp == HP - 1) | (xp == 0) | (xp == WP - 1);
        if (border) {
            u16x8 z = {0, 0, 0, 0, 0, 0, 0, 0};
            *reinterpret_cast<u16x8*>(dst) = z;
        } else {
            const float* src = x + ((size_t)b * IN_C + ch) * HW + (yp - 1) * WW + (xp - 1);
            u16x8 v;
#pragma unroll
            for (int j = 0; j < 8; ++j)
                v[j] = f2bf(src[(size_t)j * HW]);
            *reinterpret_cast<u16x8*>(dst) = v;
        }
    } else {
        int t = (blk - NXBLK) * 256 + tid;     // 0..9215
        f32x4 v = reinterpret_cast<const f32x4*>(w)[t];
#pragma unroll
        for (int j = 0; j < 4; ++j) {
            int e   = 4 * t + j;               // (oc*64+ic)*9 + tap
            int tap = e % 9;
            int p   = e / 9;                   // oc*64+ic
            wt[(size_t)tap * (OUT_C * IN_C) + p] = f2bf(v[j]);
        }
    }
}

// Implicit GEMM: wave = 16 px (one row segment) x 64 oc, K=576.
// B staged in LDS, XOR-swizzled (short-col ^ ((row&7)<<3)) -> conflict-free ds_read_b128.
// A: 16B global loads from xt (NHWC, contiguous in ic).
// D layout (m89-verified): col(oc)=l&15, row(pixel)=4*(l>>4)+reg.
__global__ __launch_bounds__(256, 2) void conv_lds(const unsigned short* __restrict__ xt,
                                                   const unsigned short* __restrict__ wt,
                                                   const float* __restrict__ bias,
                                                   float* __restrict__ out) {
    __shared__ unsigned short lw[9 * OUT_C * IN_C];    // 73728 B
    int tid = threadIdx.x;

    // bijective XCD chunk-swizzle: 392 = 8 * 49. Contiguous spatial slab per XCD.
    int bid = blockIdx.x;
    int blk = (bid & 7) * 49 + (bid >> 3);

    // stage wt (36864 shorts): 18 u16x8 per thread, swizzled
#pragma unroll
    for (int i = 0; i < 18; ++i) {
        int V   = tid + i * 256;               // vec8 index, < 4608
        int row = V >> 3;                      // tap*64 + oc
        int c   = (V & 7) << 3;                // short col within row
        u16x8 v = *reinterpret_cast<const u16x8*>(wt + (size_t)V * 8);
        int cs  = c ^ ((row & 7) << 3);
        *reinterpret_cast<u16x8*>(&lw[row * 64 + cs]) = v;
    }
    __syncthreads();

    int l  = tid & 63;
    int wv = tid >> 6;                  // wave 0..3 -> row within ytile
    int b  = blk / 196;
    int rm = blk % 196;
    int ytile = rm / 7, xtile = rm % 7;
    int y  = ytile * 4 + wv;
    int x0 = xtile * 16;
    int lm = l & 15;
    int lk = l >> 4;
    int swz = (lm & 7) << 3;

    f32x4 acc0 = {0.f, 0.f, 0.f, 0.f};
    f32x4 acc1 = {0.f, 0.f, 0.f, 0.f};
    f32x4 acc2 = {0.f, 0.f, 0.f, 0.f};
    f32x4 acc3 = {0.f, 0.f, 0.f, 0.f};

    const unsigned short* xb = xt + (((size_t)b * HP + y) * WP + x0 + lm) * IN_C + lk * 8;

#pragma unroll
    for (int r = 0; r < 3; ++r) {
#pragma unroll
        for (int s = 0; s < 3; ++s) {
            const unsigned short* xp  = xb + (r * WP + s) * IN_C;
            int tapbase = ((r * 3 + s) * OUT_C + lm) * 64;   // row*64 for f=0
#pragma unroll
            for (int icc = 0; icc < 2; ++icc) {
                int cs = (icc * 32 + lk * 8) ^ swz;
                bf16x8 a  = *reinterpret_cast<const bf16x8*>(xp + icc * 32);
                bf16x8 b0 = *reinterpret_cast<const bf16x8*>(&lw[tapbase + cs]);
                bf16x8 b1 = *reinterpret_cast<const bf16x8*>(&lw[tapbase + 16 * 64 + cs]);
                bf16x8 b2 = *reinterpret_cast<const bf16x8*>(&lw[tapbase + 32 * 64 + cs]);
                bf16x8 b3 = *reinterpret_cast<const bf16x8*>(&lw[tapbase + 48 * 64 + cs]);
                acc0 = __builtin_amdgcn_mfma_f32_16x16x32_bf16(a, b0, acc0, 0, 0, 0);
                acc1 = __builtin_amdgcn_mfma_f32_16x16x32_bf16(a, b1, acc1, 0, 0, 0);
                acc2 = __builtin_amdgcn_mfma_f32_16x16x32_bf16(a, b2, acc2, 0, 0, 0);
                acc3 = __builtin_amdgcn_mfma_f32_16x16x32_bf16(a, b3, acc3, 0, 0, 0);
            }
        }
    }

    f32x4 accs[4] = {acc0, acc1, acc2, acc3};
    int px = x0 + lk * 4;
#pragma unroll
    for (int f = 0; f < 4; ++f) {
        int oc   = f * 16 + lm;
        float bv = bias[oc];
        f32x4 v  = accs[f];
        v.x += bv; v.y += bv; v.z += bv; v.w += bv;
        *reinterpret_cast<f32x4*>(out + (((size_t)b * OUT_C + oc) * HH + y) * WW + px) = v;
    }
}

extern "C" void kernel_launch(void* const* d_in, const int* in_sizes, int n_in,
                              void* d_out, int out_size, void* d_ws, size_t ws_size,
                              hipStream_t stream) {
    const float* x    = (const float*)d_in[0];
    const float* w    = (const float*)d_in[1];
    const float* bias = (const float*)d_in[2];
    float* out        = (float*)d_out;

    unsigned short* xt = (unsigned short*)d_ws;                  // 2*114*114*64 bf16 = 3,326,976 B
    unsigned short* wt = xt + (size_t)BN * HP * WP * IN_C;       // 9*64*64 bf16 = 73,728 B

    prep_all<<<dim3(NXBLK + NWBLK), dim3(256), 0, stream>>>(x, w, xt, wt);
    conv_lds<<<dim3(NCONV), dim3(256), 0, stream>>>(xt, wt, bias, out);
}

// Round 8
// 18.326 us; speedup vs baseline: 1.2301x; 1.0245x over previous
//
#include <hip/hip_runtime.h>

// Conv2d 3x3 pad1: x(2,64,112,112) f32, w(64,64,3,3) f32, bias(64) f32 -> out(2,64,112,112) f32
// Two kernels (r3 structure, best 18.65us):
//   1) prep_all: NCHW->padded-NHWC bf16 x-transform (912 blocks)
//                + weight transform to [tap][oc][ic] bf16, PRE-SWIZZLED (ic ^ ((oc&7)<<3))
//   2) conv_lds: implicit GEMM, mfma_f32_16x16x32_bf16, wave = 16px x 64oc.
//                Weights staged via global_load_lds dwordx4 (linear copy of pre-swizzled wt
//                -- rule 21: linear dest + pre-swizzled source + swizzled read).
//                392 blocks = 8 XCD chunks x 49.

#define IN_C  64
#define OUT_C 64
#define BN    2
#define HH    112
#define WW    112
#define HP    114
#define WP    114
#define HW    (HH * WW)
#define NXBLK (BN * HP * 4)      // 912: (b, yp, channel-quad)
#define NWBLK 36                 // 36 * 256 * f32x4 = all 36864 floats of w
#define NCONV 392                // 2 * 28 * 7 tiles (4 rows x 16 cols, 4 waves)

typedef __attribute__((ext_vector_type(8))) short          bf16x8;
typedef __attribute__((ext_vector_type(8))) unsigned short u16x8;
typedef __attribute__((ext_vector_type(4))) float          f32x4;

static __device__ __forceinline__ unsigned short f2bf(float f) {
    unsigned int u = __builtin_bit_cast(unsigned int, f);
    u += 0x7FFFu + ((u >> 16) & 1u);   // round-nearest-even
    return (unsigned short)(u >> 16);
}

// blocks [0, NXBLK): x-transform. block = (b, yp, cq); thread = (xp, 8-channel group).
// blocks [NXBLK, NXBLK+NWBLK): w-transform (pre-swizzled columns).
__global__ __launch_bounds__(256) void prep_all(const float* __restrict__ x,
                                                const float* __restrict__ w,
                                                unsigned short* __restrict__ xt,
                                                unsigned short* __restrict__ wt) {
    int blk = blockIdx.x;
    int tid = threadIdx.x;
    if (blk < NXBLK) {
        int cq = blk & 3;
        int r  = blk >> 2;
        int b  = r / HP;
        int yp = r % HP;
        int xp = tid & 127;                    // 0..127, valid < 114
        int ch = cq * 16 + (tid >> 7) * 8;     // 8 channels per thread
        if (xp >= WP) return;
        unsigned short* dst = xt + (((size_t)b * HP + yp) * WP + xp) * IN_C + ch;
        bool border = (yp == 0) | (yp == HP - 1) | (xp == 0) | (xp == WP - 1);
        if (border) {
            u16x8 z = {0, 0, 0, 0, 0, 0, 0, 0};
            *reinterpret_cast<u16x8*>(dst) = z;
        } else {
            const float* src = x + ((size_t)b * IN_C + ch) * HW + (yp - 1) * WW + (xp - 1);
            u16x8 v;
#pragma unroll
            for (int j = 0; j < 8; ++j)
                v[j] = f2bf(src[(size_t)j * HW]);
            *reinterpret_cast<u16x8*>(dst) = v;
        }
    } else {
        int t = (blk - NXBLK) * 256 + tid;     // 0..9215
        f32x4 v = reinterpret_cast<const f32x4*>(w)[t];
#pragma unroll
        for (int j = 0; j < 4; ++j) {
            int e   = 4 * t + j;               // (oc*64+ic)*9 + tap
            int tap = e % 9;
            int p   = e / 9;                   // oc*64+ic
            int oc  = p >> 6, ic = p & 63;
            int col = ic ^ ((oc & 7) << 3);    // pre-swizzle (row&7 == oc&7 since tap*64%8==0)
            wt[(size_t)tap * (OUT_C * IN_C) + oc * IN_C + col] = f2bf(v[j]);
        }
    }
}

// Implicit GEMM: wave = 16 px (one row segment) x 64 oc, K=576.
// B staged linearly via global_load_lds from pre-swizzled wt; reads use ^((oc&7)<<3).
// A: 16B global loads from xt (NHWC, contiguous in ic).
// D layout (m89-verified): col(oc)=l&15, row(pixel)=4*(l>>4)+reg.
__global__ __launch_bounds__(256, 2) void conv_lds(const unsigned short* __restrict__ xt,
                                                   const unsigned short* __restrict__ wt,
                                                   const float* __restrict__ bias,
                                                   float* __restrict__ out) {
    __shared__ unsigned short lw[9 * OUT_C * IN_C];    // 73728 B
    int tid  = threadIdx.x;
    int l    = tid & 63;
    int wv   = tid >> 6;                // wave 0..3

    // bijective XCD chunk-swizzle: 392 = 8 * 49. Contiguous spatial slab per XCD.
    int bid = blockIdx.x;
    int blk = (bid & 7) * 49 + (bid >> 3);

    // stage wt -> LDS: 72 segments of 1KB; wave wv issues 18 global_load_lds dwordx4
    // (linear copy: wave-uniform LDS base + lane*16; per-lane global src).
    {
        const char* wbase = (const char*)wt;
        char*       lbase = (char*)lw;
#pragma unroll
        for (int i = 0; i < 18; ++i) {
            int seg = i * 4 + wv;              // 0..71
            const void* g = wbase + (size_t)seg * 1024 + l * 16;
            __builtin_amdgcn_global_load_lds(
                (const __attribute__((address_space(1))) unsigned int*)g,
                (__attribute__((address_space(3))) unsigned int*)(lbase + seg * 1024),
                16, 0, 0);
        }
    }
    __syncthreads();

    int b  = blk / 196;
    int rm = blk % 196;
    int ytile = rm / 7, xtile = rm % 7;
    int y  = ytile * 4 + wv;
    int x0 = xtile * 16;
    int lm = l & 15;
    int lk = l >> 4;
    int swz = (lm & 7) << 3;

    f32x4 acc0 = {0.f, 0.f, 0.f, 0.f};
    f32x4 acc1 = {0.f, 0.f, 0.f, 0.f};
    f32x4 acc2 = {0.f, 0.f, 0.f, 0.f};
    f32x4 acc3 = {0.f, 0.f, 0.f, 0.f};

    const unsigned short* xb = xt + (((size_t)b * HP + y) * WP + x0 + lm) * IN_C + lk * 8;

#pragma unroll
    for (int r = 0; r < 3; ++r) {
#pragma unroll
        for (int s = 0; s < 3; ++s) {
            const unsigned short* xp  = xb + (r * WP + s) * IN_C;
            int tapbase = ((r * 3 + s) * OUT_C + lm) * 64;   // row*64 for f=0
#pragma unroll
            for (int icc = 0; icc < 2; ++icc) {
                int cs = (icc * 32 + lk * 8) ^ swz;
                bf16x8 a  = *reinterpret_cast<const bf16x8*>(xp + icc * 32);
                bf16x8 b0 = *reinterpret_cast<const bf16x8*>(&lw[tapbase + cs]);
                bf16x8 b1 = *reinterpret_cast<const bf16x8*>(&lw[tapbase + 16 * 64 + cs]);
                bf16x8 b2 = *reinterpret_cast<const bf16x8*>(&lw[tapbase + 32 * 64 + cs]);
                bf16x8 b3 = *reinterpret_cast<const bf16x8*>(&lw[tapbase + 48 * 64 + cs]);
                acc0 = __builtin_amdgcn_mfma_f32_16x16x32_bf16(a, b0, acc0, 0, 0, 0);
                acc1 = __builtin_amdgcn_mfma_f32_16x16x32_bf16(a, b1, acc1, 0, 0, 0);
                acc2 = __builtin_amdgcn_mfma_f32_16x16x32_bf16(a, b2, acc2, 0, 0, 0);
                acc3 = __builtin_amdgcn_mfma_f32_16x16x32_bf16(a, b3, acc3, 0, 0, 0);
            }
        }
    }

    f32x4 accs[4] = {acc0, acc1, acc2, acc3};
    int px = x0 + lk * 4;
#pragma unroll
    for (int f = 0; f < 4; ++f) {
        int oc   = f * 16 + lm;
        float bv = bias[oc];
        f32x4 v  = accs[f];
        v.x += bv; v.y += bv; v.z += bv; v.w += bv;
        *reinterpret_cast<f32x4*>(out + (((size_t)b * OUT_C + oc) * HH + y) * WW + px) = v;
    }
}

extern "C" void kernel_launch(void* const* d_in, const int* in_sizes, int n_in,
                              void* d_out, int out_size, void* d_ws, size_t ws_size,
                              hipStream_t stream) {
    const float* x    = (const float*)d_in[0];
    const float* w    = (const float*)d_in[1];
    const float* bias = (const float*)d_in[2];
    float* out        = (float*)d_out;

    unsigned short* xt = (unsigned short*)d_ws;                  // 2*114*114*64 bf16 = 3,326,976 B
    unsigned short* wt = xt + (size_t)BN * HP * WP * IN_C;       // 9*64*64 bf16 = 73,728 B (16B-aligned)

    prep_all<<<dim3(NXBLK + NWBLK), dim3(256), 0, stream>>>(x, w, xt, wt);
    conv_lds<<<dim3(NCONV), dim3(256), 0, stream>>>(xt, wt, bias, out);
}